// Round 2
// baseline (153.100 us; speedup 1.0000x reference)
//
#include <hip/hip_runtime.h>
#include <math.h>

// L = 2*pi * log2(e): exp(-2pi r^2) == exp2(-L r^2)
#define LCONST 9.064720283654388f

// 5x5x5 cells of size 2.0 over [0,10)^3. Cutoff r=2: dropped terms are
// exp2(-L*4) ~ 1.2e-11 each vs theta ~0.36 -> below f32 ulp: exact.
#define NC 5
#define NCELL 125
#define DOMCAP 192   // dom pts/cell: mean 131, sigma ~11 -> 192 is +5.3 sigma
#define C1CAP 32     // C1 pts/cell/batch: mean 8.2 -> 32 is astronomically safe
#define CCAP 32

__device__ __forceinline__ float fexp2(float x) {
#if defined(__has_builtin)
#if __has_builtin(__builtin_amdgcn_exp2f)
    return __builtin_amdgcn_exp2f(x);
#else
    return exp2f(x);
#endif
#else
    return exp2f(x);
#endif
}

__device__ __forceinline__ int cell_of(float x, float y, float z) {
    int cx = (int)(x * 0.5f); cx = cx < 0 ? 0 : (cx > NC - 1 ? NC - 1 : cx);
    int cy = (int)(y * 0.5f); cy = cy < 0 ? 0 : (cy > NC - 1 ? NC - 1 : cy);
    int cz = (int)(z * 0.5f); cz = cz < 0 ? 0 : (cz > NC - 1 ? NC - 1 : cz);
    return (cx * NC + cy) * NC + cz;
}

// Scan the 27-neighborhood bins of (cx,cy,cz); all control flow is
// wave-uniform (lanes share the cell). Point loads are wave-uniform float4
// broadcasts from L1/L2. Pairs beyond r=2 inside the neighborhood just
// produce exp2(very negative)=0 -- no branching per pair.
// CRITICAL: the full exponent arg = 2L d.q - L|q|^2 - L|d|^2 = -L||d-q||^2
// must stay in ONE exp2 argument (always <= 0). Factoring exp2(d.w) out of
// the loop overflows: exp2(+huge) * exp2(-huge) = inf * 0 = NaN. (Round-1 bug.)
__device__ __forceinline__ float scan_bins(float4 d, int cx, int cy, int cz,
                                           const float4* __restrict__ P,
                                           const int* __restrict__ cnt, int cap) {
    float acc = 0.0f;
    #pragma unroll
    for (int dx = -1; dx <= 1; ++dx) {
        int x2 = cx + dx; if ((unsigned)x2 >= (unsigned)NC) continue;
        #pragma unroll
        for (int dy = -1; dy <= 1; ++dy) {
            int y2 = cy + dy; if ((unsigned)y2 >= (unsigned)NC) continue;
            int zlo = cz > 0 ? cz - 1 : 0;
            int zhi = cz < NC - 1 ? cz + 1 : NC - 1;
            int cb = (x2 * NC + y2) * NC;
            for (int z2 = zlo; z2 <= zhi; ++z2) {
                int cc = cb + z2;
                int n = min(cnt[cc], cap);      // clamp: overflowed bins can't OOB
                const float4* p = P + cc * cap;
                #pragma unroll 4
                for (int i = 0; i < n; ++i) {
                    float4 q = p[i];
                    float arg = fmaf(d.x, q.x,
                                fmaf(d.y, q.y,
                                fmaf(d.z, q.z, d.w + q.w)));   // = -L||d-q||^2 <= 0
                    acc += fexp2(arg);
                }
            }
        }
    }
    return acc;
}

// counters layout (ints): [cntD 125][cntC1 16*125][cntC 125][prod 16] = 2266 words
__global__ void k_zero(int* __restrict__ c) {
    int t = blockIdx.x * 256 + threadIdx.x;
    if (t < 2266) c[t] = 0;
}

// Bin all three point sets via atomic-append. Slot order within a bin is
// nondeterministic but sums are order-free.
__global__ void __launch_bounds__(256) k_bin(const float* __restrict__ C1,
                                             const float* __restrict__ C,
                                             const float* __restrict__ dom,
                                             float4* __restrict__ PDbin,
                                             float4* __restrict__ P1bin,
                                             float4* __restrict__ PCbin,
                                             int* __restrict__ cnts) {
    int* cntD  = cnts;
    int* cntC1 = cnts + NCELL;
    int* cntC  = cnts + NCELL + 16 * NCELL;
    int t = blockIdx.x * 256 + threadIdx.x;
    if (t < 16384) {
        float x = dom[3 * t], y = dom[3 * t + 1], z = dom[3 * t + 2];
        int cell = cell_of(x, y, z);
        int s = atomicAdd(cntD + cell, 1);
        if (s < DOMCAP)
            PDbin[cell * DOMCAP + s] = make_float4(2.0f * LCONST * x, 2.0f * LCONST * y,
                                                   2.0f * LCONST * z,
                                                   -LCONST * (x * x + y * y + z * z));
    } else if (t < 32768) {
        int j = t - 16384;
        float x = C1[3 * j], y = C1[3 * j + 1], z = C1[3 * j + 2];
        int b = j >> 10;
        int cell = cell_of(x, y, z);
        int s = atomicAdd(cntC1 + b * NCELL + cell, 1);
        if (s < C1CAP)
            P1bin[(b * NCELL + cell) * C1CAP + s] =
                make_float4(x, y, z, -LCONST * (x * x + y * y + z * z));
    } else if (t < 33792) {
        int j = t - 32768;
        float x = C[3 * j], y = C[3 * j + 1], z = C[3 * j + 2];
        int cell = cell_of(x, y, z);
        int s = atomicAdd(cntC + cell, 1);
        if (s < CCAP)
            PCbin[cell * CCAP + s] = make_float4(x, y, z, -LCONST * (x * x + y * y + z * z));
    }
}

// theta_C per binned dom slot. Block = cell (192 slots = 3 waves, each wave
// entirely within one cell -> uniform neighbor scan).
__global__ void __launch_bounds__(192) k_tc(const float4* __restrict__ PDbin,
                                            const float4* __restrict__ PCbin,
                                            const int* __restrict__ cnts,
                                            float* __restrict__ TC) {
    const int* cntD = cnts;
    const int* cntC = cnts + NCELL + 16 * NCELL;
    int cell = blockIdx.x;
    int s = threadIdx.x;
    int lane = s & 63;
    int len = min(cntD[cell], DOMCAP);
    if (s - lane >= len) return;            // wave-uniform: whole wave empty
    float4 d = PDbin[cell * DOMCAP + s];
    if (s >= len) d = make_float4(0.f, 0.f, 0.f, 0.f);   // sanitize poison
    int cx = cell / 25, cy = (cell / 5) % 5, cz = cell % 5;
    float acc = scan_bins(d, cx, cy, cz, PCbin, cntC, CCAP);
    // write all live-wave slots (finite even for pad lanes) so k_main never
    // multiplies NaN for a lane it will mask.
    TC[cell * DOMCAP + s] = acc;
}

// Wave task = (batch b, cell, 64-pt chunk). Lanes = 64 dom points of one cell.
__global__ void __launch_bounds__(256) k_main(const float4* __restrict__ PDbin,
                                              const float4* __restrict__ P1bin,
                                              const int* __restrict__ cnts,
                                              const float* __restrict__ TC,
                                              float* __restrict__ prod) {
    const int* cntD  = cnts;
    const int* cntC1 = cnts + NCELL;
    int wid = threadIdx.x >> 6, lane = threadIdx.x & 63;
    int t = blockIdx.x * 4 + wid;           // 0..5999 = ((b*125)+cell)*3+chunk
    int chunk = t % 3;
    int rest  = t / 3;
    int cell  = rest % NCELL;
    int b     = rest / NCELL;
    int len = min(cntD[cell], DOMCAP) - chunk * 64;
    if (len <= 0) return;                   // wave-uniform, no __syncthreads used
    int slot = cell * DOMCAP + chunk * 64 + lane;
    float4 d = PDbin[slot];
    if (lane >= len) d = make_float4(0.f, 0.f, 0.f, 0.f);   // sanitize poison
    int cx = cell / 25, cy = (cell / 5) % 5, cz = cell % 5;
    float acc = scan_bins(d, cx, cy, cz, P1bin + b * (NCELL * C1CAP),
                          cntC1 + b * NCELL, C1CAP);
    float v = acc * TC[slot];
    v = (lane < len) ? v : 0.0f;            // select, not multiply: NaN-safe
    for (int off = 32; off; off >>= 1) v += __shfl_down(v, off, 64);
    if (lane == 0) atomicAdd(prod + b, v);
}

__global__ void k_out(const float* __restrict__ prod, float* __restrict__ out) {
    int t = threadIdx.x;
    if (t < 16) {
        const float scale = 4.76837158203125e-4f;  // A*V/1024 = 8*(1000/16384)/1024
        float dot = prod[t] * scale;
        dot = fminf(fmaxf(dot, 0.0f), 1.0f);
        out[t] = 1.0f - dot;
    }
}

extern "C" void kernel_launch(void* const* d_in, const int* in_sizes, int n_in,
                              void* d_out, int out_size, void* d_ws, size_t ws_size,
                              hipStream_t stream) {
    const float* C1  = (const float*)d_in[0];   // (16,1024,3)
    const float* C   = (const float*)d_in[1];   // (1024,3)
    const float* dom = (const float*)d_in[2];   // (16384,3)
    float* out = (float*)d_out;                 // (16,)

    char* ws = (char*)d_ws;
    float4* PDbin = (float4*)(ws + 0);          // 125*192*16   =   384000
    float4* P1bin = (float4*)(ws + 384000);     // 16*125*32*16 =  1024000
    float4* PCbin = (float4*)(ws + 1408000);    // 125*32*16    =    64000
    float*  TC    = (float*)(ws + 1472000);     // 125*192*4    =    96000
    int*    cnts  = (int*)(ws + 1568000);       // 2266 words   ->   ~1.58MB total
    float*  prod  = (float*)(cnts + 2250);

    k_zero<<<9, 256, 0, stream>>>(cnts);
    k_bin<<<132, 256, 0, stream>>>(C1, C, dom, PDbin, P1bin, PCbin, cnts);
    k_tc<<<NCELL, 192, 0, stream>>>(PDbin, PCbin, cnts, TC);
    k_main<<<1500, 256, 0, stream>>>(PDbin, P1bin, cnts, TC, prod);
    k_out<<<1, 64, 0, stream>>>(prod, out);
}